// Round 1
// baseline (159.242 us; speedup 1.0000x reference)
//
#include <hip/hip_runtime.h>

// ---------------------------------------------------------------------------
// Self-attention: out = softmax((xWq)(xWk)^T / sqrt(64)) (xWv)
// B=4, N=4096, Din=128, Dout=64.
// Plan:
//   k1 qkv_kernel : x@W via 3-pass bf16 MFMA -> Qhi/Qlo (pre-scaled by
//                   0.125*log2e), Khi/Klo, Vt (V transposed, bf16)
//   k2 attn_kernel: flash attention, 1 wave / 64 queries, 32x32x16 bf16 MFMA,
//                   S^T = K·Q^T (3-pass), online softmax (base 2), P·V bf16.
//                   Key-split into 4 segments -> partials (O, m, l).
//   k3 merge_kernel: combine 4 segment partials.
// ---------------------------------------------------------------------------

typedef __attribute__((ext_vector_type(8))) short bf16x8;
typedef __attribute__((ext_vector_type(16))) float f32x16;
typedef unsigned short us;

__device__ __forceinline__ us f2bf(float f) {               // RTNE fp32->bf16
  unsigned u = __builtin_bit_cast(unsigned, f);
  u += 0x7FFFu + ((u >> 16) & 1u);
  return (us)(u >> 16);
}
__device__ __forceinline__ float bf2f(us h) {
  unsigned u = ((unsigned)h) << 16;
  return __builtin_bit_cast(float, u);
}
__device__ __forceinline__ f32x16 mfma(bf16x8 a, bf16x8 b, f32x16 c) {
  return __builtin_amdgcn_mfma_f32_32x32x16_bf16(a, b, c, 0, 0, 0);
}
__device__ __forceinline__ unsigned pk2(float a, float b) {
  return (unsigned)f2bf(a) | ((unsigned)f2bf(b) << 16);
}

// ---------------------------------------------------------------------------
// Kernel 1: QKV projection. 256 blocks x 256 thr. block = 128 rows x 96 cols.
// W (3*128*64 fp32) staged hi/lo-split + transposed into LDS; x rows read from
// global and hi/lo-split in-register. 3-pass bf16 MFMA (fp32-accurate).
// ---------------------------------------------------------------------------
#define WP 136  // LDS pitch (shorts) for W tiles: 272B rows, b128-aligned

__global__ __launch_bounds__(256, 1) void qkv_kernel(
    const float* __restrict__ x, const float* __restrict__ w,
    us* __restrict__ Qhi, us* __restrict__ Qlo,
    us* __restrict__ Khi, us* __restrict__ Klo, us* __restrict__ Vt)
{
  __shared__ us whi[96 * WP];
  __shared__ us wlo[96 * WP];
  const int t = threadIdx.x;
  const int rb = blockIdx.x >> 1, ch = blockIdx.x & 1;  // rowblock, col-half

  // stage W: read all 24576 fp32, keep our 96 cols, write transposed hi/lo
  for (int i = t; i < 24576; i += 256) {
    int p = i >> 13, rem = i & 8191;
    int d = rem >> 6, e = rem & 63;
    int cl = ((p << 6) + e) - ch * 96;
    if ((unsigned)cl < 96u) {
      float v = w[i];
      us hi = f2bf(v);
      whi[cl * WP + d] = hi;
      wlo[cl * WP + d] = f2bf(v - bf2f(hi));
    }
  }
  __syncthreads();

  const int wid = t >> 6, lane = t & 63;
  const int l31 = lane & 31, h = lane >> 5;
  const int rbase = rb * 128 + wid * 32;
  const float* xrow = x + (size_t)(rbase + l31) * 128;

  f32x16 acc[3] = {};
  #pragma unroll
  for (int ks = 0; ks < 8; ++ks) {           // K = 128 = 8 * 16
    const int d0 = ks * 16 + h * 8;
    const float4 xa = *(const float4*)(xrow + d0);
    const float4 xb = *(const float4*)(xrow + d0 + 4);
    const float xv[8] = {xa.x, xa.y, xa.z, xa.w, xb.x, xb.y, xb.z, xb.w};
    bf16x8 ah, al;
    #pragma unroll
    for (int j = 0; j < 8; ++j) {
      us hi = f2bf(xv[j]);
      ah[j] = (short)hi;
      al[j] = (short)f2bf(xv[j] - bf2f(hi));
    }
    #pragma unroll
    for (int nt = 0; nt < 3; ++nt) {
      bf16x8 bh = *(const bf16x8*)(&whi[(l31 + 32 * nt) * WP + d0]);
      bf16x8 bl = *(const bf16x8*)(&wlo[(l31 + 32 * nt) * WP + d0]);
      acc[nt] = mfma(ah, bh, acc[nt]);
      acc[nt] = mfma(al, bh, acc[nt]);
      acc[nt] = mfma(ah, bl, acc[nt]);
    }
  }

  // epilogue: C layout row=(r&3)+8*(r>>2)+4*h, col=l31+32*nt
  const float cq = 0.18033688011112042f;  // 0.125 * log2(e) folded into Q
  #pragma unroll
  for (int nt = 0; nt < 3; ++nt) {
    const int col = ch * 96 + 32 * nt + l31;
    const int p = col >> 6, e = col & 63;   // p uniform within nt (32 | bounds)
    #pragma unroll
    for (int r = 0; r < 16; ++r) {
      const int rl = (r & 3) + 8 * (r >> 2) + 4 * h;
      const int rg = rbase + rl;            // global row = b*4096 + n
      float v = acc[nt][r];
      if (p == 0) {
        v *= cq;
        us hi = f2bf(v);
        Qhi[(size_t)rg * 64 + e] = hi;
        Qlo[(size_t)rg * 64 + e] = f2bf(v - bf2f(hi));
      } else if (p == 1) {
        us hi = f2bf(v);
        Khi[(size_t)rg * 64 + e] = hi;
        Klo[(size_t)rg * 64 + e] = f2bf(v - bf2f(hi));
      } else {
        const int b = rg >> 12, n = rg & 4095;
        Vt[((size_t)(b * 64 + e) << 12) + n] = f2bf(v);  // [b][d][n]
      }
    }
  }
}

// ---------------------------------------------------------------------------
// Kernel 2: flash attention partials. grid 1024 (256 q-waves x 4 key-segs),
// 64 threads (1 wave). Each wave: 64 queries x 1024 keys (16 iters of 64).
// buf0: Khi tile then P (aliased). buf1: Klo tile then V (aliased; V global
// loads prefetched at iter top, staged after S-phase). Single wave per block
// => no __syncthreads needed (per-wave DS ops are in-order).
// ---------------------------------------------------------------------------
#define KP 72  // LDS pitch (shorts): 144B rows -> frag b128 reads = 8 phases

__global__ __launch_bounds__(64, 1) void attn_kernel(
    const us* __restrict__ Qhi, const us* __restrict__ Qlo,
    const us* __restrict__ Khi, const us* __restrict__ Klo,
    const us* __restrict__ Vt,
    float* __restrict__ Opart, float* __restrict__ Mpart,
    float* __restrict__ Lpart)
{
  __shared__ us buf0[64 * KP];
  __shared__ us buf1[64 * KP];
  __shared__ float alds[64];

  // XCD-aware map: XCD x serves batch x>>1 -> per-XCD K/V set = 1.5MB (L2 fits)
  const int bx = blockIdx.x;
  const int xc = bx & 7, jj = bx >> 3;
  const int b = xc >> 1;
  const int idx = (xc & 1) + 2 * jj;        // 0..255
  const int seg = idx & 3, qblk = idx >> 2;
  const int qw = b * 64 + qblk;             // 0..255 partial slot row
  const int lane = threadIdx.x;
  const int l31 = lane & 31, h = lane >> 5;

  // Q fragments (persistent): B-frag layout n=l31(+32qt), k=16*ks+8*h+j
  bf16x8 qh[2][4], ql[2][4];
  #pragma unroll
  for (int qt = 0; qt < 2; ++qt) {
    const size_t rg = (size_t)(b * 4096 + qblk * 64 + l31 + 32 * qt) * 64;
    #pragma unroll
    for (int ks = 0; ks < 4; ++ks) {
      qh[qt][ks] = *(const bf16x8*)(Qhi + rg + ks * 16 + h * 8);
      ql[qt][ks] = *(const bf16x8*)(Qlo + rg + ks * 16 + h * 8);
    }
  }
  const size_t kbase = (size_t)b * 262144;  // b*4096*64
  const size_t vbase = (size_t)b * 262144;  // b*64*4096

  f32x16 o[2][2] = {};
  float mrun[2] = {-__builtin_inff(), -__builtin_inff()};
  float lrun[2] = {0.f, 0.f};

  for (int it = 0; it < 16; ++it) {
    const int key0 = seg * 1024 + it * 64;

    // stage Khi->buf0, Klo->buf1
    #pragma unroll
    for (int i = 0; i < 8; ++i) {
      const int cid = i * 64 + lane;
      const size_t off = kbase + (size_t)(key0 + (cid >> 3)) * 64 + (cid & 7) * 8;
      bf16x8 a = *(const bf16x8*)(Khi + off);
      bf16x8 c = *(const bf16x8*)(Klo + off);
      const int loff = (cid >> 3) * KP + (cid & 7) * 8;
      *(bf16x8*)(&buf0[loff]) = a;
      *(bf16x8*)(&buf1[loff]) = c;
    }
    // prefetch V tile into regs (staged into buf1 after S-phase)
    bf16x8 vv[8];
    #pragma unroll
    for (int i = 0; i < 8; ++i) {
      const int cid = i * 64 + lane;
      vv[i] = *(const bf16x8*)(Vt + vbase + (size_t)(cid >> 3) * 4096 + key0 +
                               (cid & 7) * 8);
    }

    // S^T = K_tile · Q'^T  (3-pass hi/lo)
    f32x16 s[2][2] = {};
    #pragma unroll
    for (int m = 0; m < 2; ++m) {
      #pragma unroll
      for (int ks = 0; ks < 4; ++ks) {
        const int off = (32 * m + l31) * KP + ks * 16 + h * 8;
        bf16x8 ah = *(const bf16x8*)(&buf0[off]);
        bf16x8 al = *(const bf16x8*)(&buf1[off]);
        #pragma unroll
        for (int qt = 0; qt < 2; ++qt) {
          s[m][qt] = mfma(ah, qh[qt][ks], s[m][qt]);
          s[m][qt] = mfma(al, qh[qt][ks], s[m][qt]);
          s[m][qt] = mfma(ah, ql[qt][ks], s[m][qt]);
        }
      }
    }

    // online softmax (base-2; scale pre-folded into Q). Lane owns q=l31+32qt,
    // holds 32 of its 64 key-scores; partner lane (xor 32) holds the rest.
    float alpha[2];
    #pragma unroll
    for (int qt = 0; qt < 2; ++qt) {
      float vm = -__builtin_inff();
      #pragma unroll
      for (int r = 0; r < 16; ++r)
        vm = fmaxf(vm, fmaxf(s[0][qt][r], s[1][qt][r]));
      vm = fmaxf(vm, __shfl_xor(vm, 32));
      const float mnew = fmaxf(mrun[qt], vm);
      alpha[qt] = exp2f(mrun[qt] - mnew);
      float sum = 0.f;
      #pragma unroll
      for (int r = 0; r < 16; ++r) {
        const float p0 = exp2f(s[0][qt][r] - mnew);
        const float p1 = exp2f(s[1][qt][r] - mnew);
        s[0][qt][r] = p0;
        s[1][qt][r] = p1;
        sum += p0 + p1;
      }
      sum += __shfl_xor(sum, 32);
      lrun[qt] = lrun[qt] * alpha[qt] + sum;
      mrun[qt] = mnew;
    }

    // write P into buf0 (over Khi): row q=l31+32qt, 4 consecutive keys/pack
    #pragma unroll
    for (int qt = 0; qt < 2; ++qt) {
      #pragma unroll
      for (int m = 0; m < 2; ++m) {
        #pragma unroll
        for (int g = 0; g < 4; ++g) {
          uint2 u;
          u.x = pk2(s[m][qt][4 * g + 0], s[m][qt][4 * g + 1]);
          u.y = pk2(s[m][qt][4 * g + 2], s[m][qt][4 * g + 3]);
          *(uint2*)(&buf0[(l31 + 32 * qt) * KP + 32 * m + 8 * g + 4 * h]) = u;
        }
      }
    }
    // stage V into buf1 (over Klo)
    #pragma unroll
    for (int i = 0; i < 8; ++i) {
      const int cid = i * 64 + lane;
      *(bf16x8*)(&buf1[(cid >> 3) * KP + (cid & 7) * 8]) = vv[i];
    }

    // rescale O by alpha (skip when all-ones; LDS broadcast to C-layout rows)
    if (__any((alpha[0] != 1.f) || (alpha[1] != 1.f))) {
      alds[lane] = h ? alpha[1] : alpha[0];  // alds[q] = alpha for q
      #pragma unroll
      for (int qt = 0; qt < 2; ++qt) {
        #pragma unroll
        for (int g = 0; g < 4; ++g) {
          const float4 af = *(const float4*)(&alds[32 * qt + 8 * g + 4 * h]);
          #pragma unroll
          for (int rr = 0; rr < 4; ++rr) {
            const int r = 4 * g + rr;
            const float a = (rr == 0) ? af.x : (rr == 1) ? af.y
                           : (rr == 2) ? af.z : af.w;
            o[qt][0][r] *= a;
            o[qt][1][r] *= a;
          }
        }
      }
    }

    // PV: O[q][d] += P[q][key] * V[key][d]
    #pragma unroll
    for (int ks = 0; ks < 4; ++ks) {
      const int fo = ks * 16 + h * 8;
      bf16x8 p0 = *(const bf16x8*)(&buf0[l31 * KP + fo]);
      bf16x8 p1 = *(const bf16x8*)(&buf0[(l31 + 32) * KP + fo]);
      bf16x8 w0 = *(const bf16x8*)(&buf1[l31 * KP + fo]);
      bf16x8 w1 = *(const bf16x8*)(&buf1[(l31 + 32) * KP + fo]);
      o[0][0] = mfma(p0, w0, o[0][0]);
      o[0][1] = mfma(p0, w1, o[0][1]);
      o[1][0] = mfma(p1, w0, o[1][0]);
      o[1][1] = mfma(p1, w1, o[1][1]);
    }
  }

  // store partials (unnormalized O + per-q m,l)
  const size_t pb = (size_t)(qw * 4 + seg);
  float* op = Opart + pb * 4096;
  #pragma unroll
  for (int qt = 0; qt < 2; ++qt) {
    #pragma unroll
    for (int dt = 0; dt < 2; ++dt) {
      #pragma unroll
      for (int r = 0; r < 16; ++r) {
        const int q_l = 32 * qt + (r & 3) + 8 * (r >> 2) + 4 * h;
        op[q_l * 64 + l31 + 32 * dt] = o[qt][dt][r];
      }
    }
  }
  Mpart[pb * 64 + lane] = h ? mrun[1] : mrun[0];
  Lpart[pb * 64 + lane] = h ? lrun[1] : lrun[0];
}

// ---------------------------------------------------------------------------
// Kernel 3: merge 4 key-segment partials. 262144 threads, 4 floats each.
// ---------------------------------------------------------------------------
__global__ __launch_bounds__(256, 1) void merge_kernel(
    const float* __restrict__ Opart, const float* __restrict__ Mpart,
    const float* __restrict__ Lpart, float* __restrict__ out)
{
  const int tg = blockIdx.x * 256 + threadIdx.x;
  const int q = tg >> 4, dc = (tg & 15) * 4;
  const int qw = q >> 6, ql = q & 63;
  const int base = qw * 4;
  const float m0 = Mpart[(base + 0) * 64 + ql];
  const float m1 = Mpart[(base + 1) * 64 + ql];
  const float m2 = Mpart[(base + 2) * 64 + ql];
  const float m3 = Mpart[(base + 3) * 64 + ql];
  const float M = fmaxf(fmaxf(m0, m1), fmaxf(m2, m3));
  const float w0 = exp2f(m0 - M), w1 = exp2f(m1 - M);
  const float w2 = exp2f(m2 - M), w3 = exp2f(m3 - M);
  const float den = w0 * Lpart[(base + 0) * 64 + ql] +
                    w1 * Lpart[(base + 1) * 64 + ql] +
                    w2 * Lpart[(base + 2) * 64 + ql] +
                    w3 * Lpart[(base + 3) * 64 + ql];
  const float inv = 1.f / den;
  const float4 r0 = *(const float4*)(Opart + (size_t)(base + 0) * 4096 + ql * 64 + dc);
  const float4 r1 = *(const float4*)(Opart + (size_t)(base + 1) * 4096 + ql * 64 + dc);
  const float4 r2 = *(const float4*)(Opart + (size_t)(base + 2) * 4096 + ql * 64 + dc);
  const float4 r3 = *(const float4*)(Opart + (size_t)(base + 3) * 4096 + ql * 64 + dc);
  float4 res;
  res.x = (w0 * r0.x + w1 * r1.x + w2 * r2.x + w3 * r3.x) * inv;
  res.y = (w0 * r0.y + w1 * r1.y + w2 * r2.y + w3 * r3.y) * inv;
  res.z = (w0 * r0.z + w1 * r1.z + w2 * r2.z + w3 * r3.z) * inv;
  res.w = (w0 * r0.w + w1 * r1.w + w2 * r2.w + w3 * r3.w) * inv;
  *(float4*)(out + (size_t)q * 64 + dc) = res;
}

// ---------------------------------------------------------------------------
extern "C" void kernel_launch(void* const* d_in, const int* in_sizes, int n_in,
                              void* d_out, int out_size, void* d_ws,
                              size_t ws_size, hipStream_t stream)
{
  const float* x = (const float*)d_in[0];
  const float* w = (const float*)d_in[1];
  float* out = (float*)d_out;
  char* ws = (char*)d_ws;

  const size_t T = 2097152;  // bytes per bf16 [4,4096,64] tensor
  us* Qhi = (us*)(ws + 0 * T);
  us* Qlo = (us*)(ws + 1 * T);
  us* Khi = (us*)(ws + 2 * T);
  us* Klo = (us*)(ws + 3 * T);
  us* Vt  = (us*)(ws + 4 * T);
  float* Opart = (float*)(ws + 5 * T);                      // 16,777,216 B
  float* Mpart = (float*)(ws + 5 * T + 16777216);           //    262,144 B
  float* Lpart = (float*)(ws + 5 * T + 16777216 + 262144);  //    262,144 B
  // total workspace use: ~26.5 MiB

  hipLaunchKernelGGL(qkv_kernel, dim3(256), dim3(256), 0, stream,
                     x, w, Qhi, Qlo, Khi, Klo, Vt);
  hipLaunchKernelGGL(attn_kernel, dim3(1024), dim3(64), 0, stream,
                     Qhi, Qlo, Khi, Klo, Vt, Opart, Mpart, Lpart);
  hipLaunchKernelGGL(merge_kernel, dim3(1024), dim3(256), 0, stream,
                     Opart, Mpart, Lpart, out);
}